// Round 1
// baseline (1060.835 us; speedup 1.0000x reference)
//
#include <hip/hip_runtime.h>
#include <math.h>

#define NN 50000
#define NE 800000

__device__ __forceinline__ unsigned fkey(float f) {
    unsigned u = __float_as_uint(f);
    return (u & 0x80000000u) ? ~u : (u | 0x80000000u);
}
__device__ __forceinline__ float funkey(unsigned k) {
    unsigned u = (k & 0x80000000u) ? (k & 0x7FFFFFFFu) : ~k;
    return __uint_as_float(u);
}
__device__ __forceinline__ float elu1(float v) {
    return v > 0.0f ? v : expm1f(v);
}

// P1[n][16] = x[n][0:64] @ W_pre[0:64][16] + b_pre
__global__ void pre1_kernel(const float* __restrict__ x,
                            const float* __restrict__ Wp,   // [65][16], rows 0..63 used
                            const float* __restrict__ bp,   // [16]
                            float* __restrict__ P1) {
    __shared__ float sW[64 * 16];
    __shared__ float sb[16];
    for (int i = threadIdx.x; i < 64 * 16; i += blockDim.x) sW[i] = Wp[i];
    if (threadIdx.x < 16) sb[threadIdx.x] = bp[threadIdx.x];
    __syncthreads();
    int n = blockIdx.x * blockDim.x + threadIdx.x;
    if (n >= NN) return;
    float acc[16];
#pragma unroll
    for (int k = 0; k < 16; ++k) acc[k] = sb[k];
    const float4* xr = (const float4*)(x + (size_t)n * 64);
#pragma unroll
    for (int j4 = 0; j4 < 16; ++j4) {
        float4 xv = xr[j4];
        const float* w = &sW[j4 * 4 * 16];
#pragma unroll
        for (int k = 0; k < 16; ++k) acc[k] += xv.x * w[k];
#pragma unroll
        for (int k = 0; k < 16; ++k) acc[k] += xv.y * w[16 + k];
#pragma unroll
        for (int k = 0; k < 16; ++k) acc[k] += xv.z * w[32 + k];
#pragma unroll
        for (int k = 0; k < 16; ++k) acc[k] += xv.w * w[48 + k];
    }
    float4* o = (float4*)(P1 + (size_t)n * 16);
    o[0] = make_float4(acc[0], acc[1], acc[2], acc[3]);
    o[1] = make_float4(acc[4], acc[5], acc[6], acc[7]);
    o[2] = make_float4(acc[8], acc[9], acc[10], acc[11]);
    o[3] = make_float4(acc[12], acc[13], acc[14], acc[15]);
}

// Per edge: t = relu(P[src] + ea*wlast); m = t @ Wn + bn; atomic scatter-max(keys) into agg[dst]
__global__ void edge_kernel(const int* __restrict__ ei,     // [2][NE] (int32)
                            const float* __restrict__ ea,   // [NE]
                            const float* __restrict__ P,    // [NN][16]
                            const float* __restrict__ wlast,// [16] last row of W_pre
                            const float* __restrict__ Wn,   // [16][16]
                            const float* __restrict__ bn,   // [16]
                            unsigned* __restrict__ agg) {   // [NN][16] keys, pre-zeroed
    __shared__ float sWn[256];
    __shared__ float swl[16];
    __shared__ float sbn[16];
    for (int i = threadIdx.x; i < 256; i += blockDim.x) sWn[i] = Wn[i];
    if (threadIdx.x < 16) { swl[threadIdx.x] = wlast[threadIdx.x]; sbn[threadIdx.x] = bn[threadIdx.x]; }
    __syncthreads();
    int e = blockIdx.x * blockDim.x + threadIdx.x;
    if (e >= NE) return;
    int src = ei[e];
    int dst = ei[NE + e];
    float a = ea[e];
    const float4* pr = (const float4*)(P + (size_t)src * 16);
    float4 v0 = pr[0], v1 = pr[1], v2 = pr[2], v3 = pr[3];
    float t[16] = {v0.x, v0.y, v0.z, v0.w, v1.x, v1.y, v1.z, v1.w,
                   v2.x, v2.y, v2.z, v2.w, v3.x, v3.y, v3.z, v3.w};
#pragma unroll
    for (int j = 0; j < 16; ++j) t[j] = fmaxf(fmaf(a, swl[j], t[j]), 0.0f);
    unsigned* ag = agg + (size_t)dst * 16;
#pragma unroll
    for (int k = 0; k < 16; ++k) {
        float m = sbn[k];
#pragma unroll
        for (int j = 0; j < 16; ++j) m = fmaf(t[j], sWn[j * 16 + k], m);
        atomicMax(ag + k, fkey(m));
    }
}

// decode agg1 -> @Wo1+bo1 -> elu(elu(.)) -> @Wp2[0:16]+bp2 -> P2
__global__ void mid_kernel(const unsigned* __restrict__ agg1,
                           const float* __restrict__ Wo,  // [16][16]
                           const float* __restrict__ bo,  // [16]
                           const float* __restrict__ Wp2, // [17][16], rows 0..15 used
                           const float* __restrict__ bp2, // [16]
                           float* __restrict__ P2) {
    __shared__ float sWo[256], sWp[256], sbo[16], sbp[16];
    for (int i = threadIdx.x; i < 256; i += blockDim.x) { sWo[i] = Wo[i]; sWp[i] = Wp2[i]; }
    if (threadIdx.x < 16) { sbo[threadIdx.x] = bo[threadIdx.x]; sbp[threadIdx.x] = bp2[threadIdx.x]; }
    __syncthreads();
    int n = blockIdx.x * blockDim.x + threadIdx.x;
    if (n >= NN) return;
    float g[16];
#pragma unroll
    for (int j = 0; j < 16; ++j) {
        float v = funkey(agg1[(size_t)n * 16 + j]);
        g[j] = isfinite(v) ? v : 0.0f;
    }
    float h[16];
#pragma unroll
    for (int k = 0; k < 16; ++k) {
        float o = sbo[k];
#pragma unroll
        for (int j = 0; j < 16; ++j) o = fmaf(g[j], sWo[j * 16 + k], o);
        h[k] = elu1(elu1(o));
    }
    float p[16];
#pragma unroll
    for (int c = 0; c < 16; ++c) {
        float o = sbp[c];
#pragma unroll
        for (int k = 0; k < 16; ++k) o = fmaf(h[k], sWp[k * 16 + c], o);
        p[c] = o;
    }
    float4* out = (float4*)(P2 + (size_t)n * 16);
    out[0] = make_float4(p[0], p[1], p[2], p[3]);
    out[1] = make_float4(p[4], p[5], p[6], p[7]);
    out[2] = make_float4(p[8], p[9], p[10], p[11]);
    out[3] = make_float4(p[12], p[13], p[14], p[15]);
}

// decode agg2 -> @Wo2+bo2 -> log_softmax -> out
__global__ void final_kernel(const unsigned* __restrict__ agg2,
                             const float* __restrict__ Wo,  // [16][16]
                             const float* __restrict__ bo,  // [16]
                             float* __restrict__ out) {
    __shared__ float sWo[256], sbo[16];
    for (int i = threadIdx.x; i < 256; i += blockDim.x) sWo[i] = Wo[i];
    if (threadIdx.x < 16) sbo[threadIdx.x] = bo[threadIdx.x];
    __syncthreads();
    int n = blockIdx.x * blockDim.x + threadIdx.x;
    if (n >= NN) return;
    float g[16];
#pragma unroll
    for (int j = 0; j < 16; ++j) {
        float v = funkey(agg2[(size_t)n * 16 + j]);
        g[j] = isfinite(v) ? v : 0.0f;
    }
    float o[16];
    float mx = -1e30f;
#pragma unroll
    for (int k = 0; k < 16; ++k) {
        float v = sbo[k];
#pragma unroll
        for (int j = 0; j < 16; ++j) v = fmaf(g[j], sWo[j * 16 + k], v);
        o[k] = v;
        mx = fmaxf(mx, v);
    }
    float s = 0.0f;
#pragma unroll
    for (int k = 0; k < 16; ++k) s += expf(o[k] - mx);
    float ls = logf(s) + mx;
    float4* op = (float4*)(out + (size_t)n * 16);
#pragma unroll
    for (int q = 0; q < 4; ++q)
        op[q] = make_float4(o[q * 4 + 0] - ls, o[q * 4 + 1] - ls, o[q * 4 + 2] - ls, o[q * 4 + 3] - ls);
}

extern "C" void kernel_launch(void* const* d_in, const int* in_sizes, int n_in,
                              void* d_out, int out_size, void* d_ws, size_t ws_size,
                              hipStream_t stream) {
    const float* x         = (const float*)d_in[0];
    const float* edge_attr = (const float*)d_in[1];
    const int*   edge_index= (const int*)  d_in[2];
    const float* W_pre1 = (const float*)d_in[3];
    const float* b_pre1 = (const float*)d_in[4];
    const float* W_net1 = (const float*)d_in[5];
    const float* b_net1 = (const float*)d_in[6];
    const float* W_out1 = (const float*)d_in[7];
    const float* b_out1 = (const float*)d_in[8];
    const float* W_pre2 = (const float*)d_in[9];
    const float* b_pre2 = (const float*)d_in[10];
    const float* W_net2 = (const float*)d_in[11];
    const float* b_net2 = (const float*)d_in[12];
    const float* W_out2 = (const float*)d_in[13];
    const float* b_out2 = (const float*)d_in[14];

    float*    P   = (float*)d_ws;                                   // [NN][16]
    unsigned* agg = (unsigned*)((char*)d_ws + (size_t)NN * 16 * 4); // [NN][16] keys

    const int NODE_BLOCKS = (NN + 255) / 256;
    const int EDGE_BLOCKS = (NE + 255) / 256;

    // ----- layer 1 -----
    hipMemsetAsync(agg, 0, (size_t)NN * 16 * 4, stream);
    pre1_kernel<<<NODE_BLOCKS, 256, 0, stream>>>(x, W_pre1, b_pre1, P);
    edge_kernel<<<EDGE_BLOCKS, 256, 0, stream>>>(edge_index, edge_attr, P,
                                                 W_pre1 + 64 * 16, W_net1, b_net1, agg);
    // mid: agg1 -> P2 (reuse P buffer)
    mid_kernel<<<NODE_BLOCKS, 256, 0, stream>>>(agg, W_out1, b_out1, W_pre2, b_pre2, P);

    // ----- layer 2 -----
    hipMemsetAsync(agg, 0, (size_t)NN * 16 * 4, stream);
    edge_kernel<<<EDGE_BLOCKS, 256, 0, stream>>>(edge_index, edge_attr, P,
                                                 W_pre2 + 16 * 16, W_net2, b_net2, agg);
    final_kernel<<<NODE_BLOCKS, 256, 0, stream>>>(agg, W_out2, b_out2, (float*)d_out);
}

// Round 2
// 236.452 us; speedup vs baseline: 4.4865x; 4.4865x over previous
//
#include <hip/hip_runtime.h>
#include <math.h>

#define NN 50000
#define NE 800000

__device__ __forceinline__ float elu1(float v) {
    return v > 0.0f ? v : expm1f(v);
}

// ---------------- setup: CSR by dst ----------------

__global__ void hist_kernel(const int* __restrict__ ei, int* __restrict__ deg) {
    int e = blockIdx.x * blockDim.x + threadIdx.x;
    if (e < NE) atomicAdd(&deg[ei[NE + e]], 1);
}

// exclusive scan of deg[0..NN) -> start[0..NN], also copy to cursor
__global__ void scan_kernel(const int* __restrict__ deg,
                            int* __restrict__ start,
                            int* __restrict__ cursor) {
    __shared__ int s[1024];
    int tid = threadIdx.x;
    int carry = 0;
    for (int base = 0; base < NN; base += 1024) {
        int i = base + tid;
        int v = (i < NN) ? deg[i] : 0;
        s[tid] = v;
        __syncthreads();
#pragma unroll
        for (int off = 1; off < 1024; off <<= 1) {
            int t = (tid >= off) ? s[tid - off] : 0;
            __syncthreads();
            s[tid] += t;
            __syncthreads();
        }
        int excl = carry + s[tid] - v;
        if (i < NN) { start[i] = excl; cursor[i] = excl; }
        carry += s[1023];   // uniform across threads; last op was a sync
        __syncthreads();
    }
    if (tid == 0) start[NN] = carry;
}

__global__ void scatter_kernel(const int* __restrict__ ei,
                               const float* __restrict__ ea,
                               int* __restrict__ cursor,
                               int2* __restrict__ sp) {
    int e = blockIdx.x * blockDim.x + threadIdx.x;
    if (e >= NE) return;
    int d = ei[NE + e];
    int pos = atomicAdd(&cursor[d], 1);
    sp[pos] = make_int2(ei[e], __float_as_int(ea[e]));
}

// ---------------- node pre-projection (layer 1) ----------------
// P1[n][16] = x[n][0:64] @ W_pre[0:64][16] + b_pre
__global__ void pre1_kernel(const float* __restrict__ x,
                            const float* __restrict__ Wp,   // [65][16]
                            const float* __restrict__ bp,   // [16]
                            float* __restrict__ P1) {
    __shared__ float sW[64 * 16];
    __shared__ float sb[16];
    for (int i = threadIdx.x; i < 64 * 16; i += blockDim.x) sW[i] = Wp[i];
    if (threadIdx.x < 16) sb[threadIdx.x] = bp[threadIdx.x];
    __syncthreads();
    int n = blockIdx.x * blockDim.x + threadIdx.x;
    if (n >= NN) return;
    float acc[16];
#pragma unroll
    for (int k = 0; k < 16; ++k) acc[k] = sb[k];
    const float4* xr = (const float4*)(x + (size_t)n * 64);
#pragma unroll
    for (int j4 = 0; j4 < 16; ++j4) {
        float4 xv = xr[j4];
        const float* w = &sW[j4 * 4 * 16];
#pragma unroll
        for (int k = 0; k < 16; ++k) acc[k] += xv.x * w[k];
#pragma unroll
        for (int k = 0; k < 16; ++k) acc[k] += xv.y * w[16 + k];
#pragma unroll
        for (int k = 0; k < 16; ++k) acc[k] += xv.z * w[32 + k];
#pragma unroll
        for (int k = 0; k < 16; ++k) acc[k] += xv.w * w[48 + k];
    }
    float4* o = (float4*)(P1 + (size_t)n * 16);
    o[0] = make_float4(acc[0], acc[1], acc[2], acc[3]);
    o[1] = make_float4(acc[4], acc[5], acc[6], acc[7]);
    o[2] = make_float4(acc[8], acc[9], acc[10], acc[11]);
    o[3] = make_float4(acc[12], acc[13], acc[14], acc[15]);
}

// ---------------- fused gather-max + node MLP ----------------
// 4 threads per node; each owns 4 output dims. MODE 0: layer1 (elu(elu(@Wo+bo)) @ Wpn + bpn -> P2)
// MODE 1: layer2 (@Wo+bo -> log_softmax -> out)
template <int MODE>
__global__ void gather_kernel(const int2* __restrict__ sp,     // [NE] (src, ea) sorted by dst
                              const int* __restrict__ start,   // [NN+1]
                              const float* __restrict__ Pin,   // [NN][16]
                              const float* __restrict__ wl,    // [16] last row of W_pre
                              const float* __restrict__ Wn,    // [16][16]
                              const float* __restrict__ bn,    // [16]
                              const float* __restrict__ Wo,    // [16][16]
                              const float* __restrict__ bo,    // [16]
                              const float* __restrict__ Wpn,   // [17][16] rows 0..15 (MODE 0)
                              const float* __restrict__ bpn,   // [16] (MODE 0)
                              float* __restrict__ out) {
    __shared__ float swl[16], sbn[16], sbo[16], sbpn[16];
    __shared__ float sWn[256], sWo[256], sWpn[256];
    __shared__ float sAgg[64][17];
    int tid = threadIdx.x;
    if (tid < 256) {
        sWn[tid] = Wn[tid];
        sWo[tid] = Wo[tid];
        if (MODE == 0) sWpn[tid] = Wpn[tid];
    }
    if (tid < 16) {
        swl[tid] = wl[tid];
        sbn[tid] = bn[tid];
        sbo[tid] = bo[tid];
        if (MODE == 0) sbpn[tid] = bpn[tid];
    }
    __syncthreads();

    int l = tid >> 2;        // local node 0..63
    int g = tid & 3;         // dim group 0..3
    int n = blockIdx.x * 64 + l;
    bool valid = (n < NN);

    float acc[4] = {-INFINITY, -INFINITY, -INFINITY, -INFINITY};
    int s0 = 0, s1 = 0;
    if (valid) { s0 = start[n]; s1 = start[n + 1]; }

    int s = s0;
    int2 sv = (s < s1) ? sp[s] : make_int2(0, 0);
    while (s < s1) {
        int2 cur = sv;
        ++s;
        if (s < s1) sv = sp[s];                 // prefetch next pair
        float a = __int_as_float(cur.y);
        const float4* pr = (const float4*)(Pin + (size_t)cur.x * 16);
        float4 v0 = pr[0], v1 = pr[1], v2 = pr[2], v3 = pr[3];
        float t[16] = {v0.x, v0.y, v0.z, v0.w, v1.x, v1.y, v1.z, v1.w,
                       v2.x, v2.y, v2.z, v2.w, v3.x, v3.y, v3.z, v3.w};
#pragma unroll
        for (int j = 0; j < 16; ++j) t[j] = fmaxf(fmaf(a, swl[j], t[j]), 0.0f);
#pragma unroll
        for (int q = 0; q < 4; ++q) {
            int c = g * 4 + q;
            float m = sbn[c];
#pragma unroll
            for (int j = 0; j < 16; ++j) m = fmaf(t[j], sWn[j * 16 + c], m);
            acc[q] = fmaxf(acc[q], m);
        }
    }
    bool empty = (s1 == s0);
#pragma unroll
    for (int q = 0; q < 4; ++q) sAgg[l][g * 4 + q] = empty ? 0.0f : acc[q];
    __syncthreads();

    if (MODE == 0) {
        float h[4];
#pragma unroll
        for (int q = 0; q < 4; ++q) {
            int c = g * 4 + q;
            float o = sbo[c];
#pragma unroll
            for (int j = 0; j < 16; ++j) o = fmaf(sAgg[l][j], sWo[j * 16 + c], o);
            h[q] = elu1(elu1(o));
        }
        __syncthreads();
#pragma unroll
        for (int q = 0; q < 4; ++q) sAgg[l][g * 4 + q] = h[q];
        __syncthreads();
        float p[4];
#pragma unroll
        for (int q = 0; q < 4; ++q) {
            int c = g * 4 + q;
            float o = sbpn[c];
#pragma unroll
            for (int k = 0; k < 16; ++k) o = fmaf(sAgg[l][k], sWpn[k * 16 + c], o);
            p[q] = o;
        }
        if (valid) {
            float4* op = (float4*)(out + (size_t)n * 16 + g * 4);
            *op = make_float4(p[0], p[1], p[2], p[3]);
        }
    } else {
        float oo[4];
#pragma unroll
        for (int q = 0; q < 4; ++q) {
            int c = g * 4 + q;
            float o = sbo[c];
#pragma unroll
            for (int j = 0; j < 16; ++j) o = fmaf(sAgg[l][j], sWo[j * 16 + c], o);
            oo[q] = o;
        }
        __syncthreads();
#pragma unroll
        for (int q = 0; q < 4; ++q) sAgg[l][g * 4 + q] = oo[q];
        __syncthreads();
        float mx = -INFINITY;
#pragma unroll
        for (int j = 0; j < 16; ++j) mx = fmaxf(mx, sAgg[l][j]);
        float sum = 0.0f;
#pragma unroll
        for (int j = 0; j < 16; ++j) sum += expf(sAgg[l][j] - mx);
        float ls = logf(sum) + mx;
        if (valid) {
            float4* op = (float4*)(out + (size_t)n * 16 + g * 4);
            *op = make_float4(oo[0] - ls, oo[1] - ls, oo[2] - ls, oo[3] - ls);
        }
    }
}

extern "C" void kernel_launch(void* const* d_in, const int* in_sizes, int n_in,
                              void* d_out, int out_size, void* d_ws, size_t ws_size,
                              hipStream_t stream) {
    const float* x         = (const float*)d_in[0];
    const float* edge_attr = (const float*)d_in[1];
    const int*   edge_index= (const int*)  d_in[2];
    const float* W_pre1 = (const float*)d_in[3];
    const float* b_pre1 = (const float*)d_in[4];
    const float* W_net1 = (const float*)d_in[5];
    const float* b_net1 = (const float*)d_in[6];
    const float* W_out1 = (const float*)d_in[7];
    const float* b_out1 = (const float*)d_in[8];
    const float* W_pre2 = (const float*)d_in[9];
    const float* b_pre2 = (const float*)d_in[10];
    const float* W_net2 = (const float*)d_in[11];
    const float* b_net2 = (const float*)d_in[12];
    const float* W_out2 = (const float*)d_in[13];
    const float* b_out2 = (const float*)d_in[14];

    char* ws = (char*)d_ws;
    float* P1    = (float*)(ws);                         // 3,200,000 B
    float* P2    = (float*)(ws + 3200000);               // 3,200,000 B
    int2*  sp    = (int2*) (ws + 6400000);               // 6,400,000 B
    int*   start = (int*)  (ws + 12800000);              // 200,004 B
    int*   cursor= (int*)  (ws + 13000256);              // 200,000 B
    int*   deg   = (int*)  (ws + 13200512);              // 200,000 B

    const int EDGE_BLOCKS = (NE + 255) / 256;   // 3125
    const int NODE_BLOCKS = (NN + 255) / 256;   // 196
    const int GATH_BLOCKS = (NN + 63) / 64;     // 782

    // ----- CSR setup (shared by both layers) -----
    hipMemsetAsync(deg, 0, (size_t)NN * 4, stream);
    hist_kernel<<<EDGE_BLOCKS, 256, 0, stream>>>(edge_index, deg);
    scan_kernel<<<1, 1024, 0, stream>>>(deg, start, cursor);
    scatter_kernel<<<EDGE_BLOCKS, 256, 0, stream>>>(edge_index, edge_attr, cursor, sp);

    // ----- layer 1 -----
    pre1_kernel<<<NODE_BLOCKS, 256, 0, stream>>>(x, W_pre1, b_pre1, P1);
    gather_kernel<0><<<GATH_BLOCKS, 256, 0, stream>>>(sp, start, P1,
        W_pre1 + 64 * 16, W_net1, b_net1, W_out1, b_out1, W_pre2, b_pre2, P2);

    // ----- layer 2 -----
    gather_kernel<1><<<GATH_BLOCKS, 256, 0, stream>>>(sp, start, P2,
        W_pre2 + 16 * 16, W_net2, b_net2, W_out2, b_out2, nullptr, nullptr,
        (float*)d_out);
}

// Round 3
// 156.446 us; speedup vs baseline: 6.7809x; 1.5114x over previous
//
#include <hip/hip_runtime.h>
#include <math.h>

#define NN 50000
#define NE 800000
#define SCAN_BLK 196   // ceil(NN/256)

__device__ __forceinline__ float elu1(float v) {
    return v > 0.0f ? v : expm1f(v);
}

// ---------------- setup: CSR by dst ----------------

__global__ void hist_kernel(const int* __restrict__ ei, int* __restrict__ deg) {
    int e = blockIdx.x * blockDim.x + threadIdx.x;
    if (e < NE) atomicAdd(&deg[ei[NE + e]], 1);
}

// phase A: per-block sums of deg
__global__ void scan_reduce_kernel(const int* __restrict__ deg, int* __restrict__ bsum) {
    __shared__ int s[256];
    int i = blockIdx.x * 256 + threadIdx.x;
    s[threadIdx.x] = (i < NN) ? deg[i] : 0;
    __syncthreads();
    for (int off = 128; off > 0; off >>= 1) {
        if (threadIdx.x < off) s[threadIdx.x] += s[threadIdx.x + off];
        __syncthreads();
    }
    if (threadIdx.x == 0) bsum[blockIdx.x] = s[0];
}

// phase B: exclusive scan of bsum[0..SCAN_BLK) -> boff; total -> start[NN]
__global__ void scan_partials_kernel(const int* __restrict__ bsum,
                                     int* __restrict__ boff,
                                     int* __restrict__ start) {
    __shared__ int s[256];
    int tid = threadIdx.x;
    int v = (tid < SCAN_BLK) ? bsum[tid] : 0;
    s[tid] = v;
    __syncthreads();
#pragma unroll
    for (int off = 1; off < 256; off <<= 1) {
        int t = (tid >= off) ? s[tid - off] : 0;
        __syncthreads();
        s[tid] += t;
        __syncthreads();
    }
    if (tid < SCAN_BLK) boff[tid] = s[tid] - v;
    if (tid == 255) start[NN] = s[255];
}

// phase C: per-block exclusive scan + block offset -> start, cursor
__global__ void scan_apply_kernel(const int* __restrict__ deg,
                                  const int* __restrict__ boff,
                                  int* __restrict__ start,
                                  int* __restrict__ cursor) {
    __shared__ int s[256];
    int tid = threadIdx.x;
    int i = blockIdx.x * 256 + tid;
    int v = (i < NN) ? deg[i] : 0;
    s[tid] = v;
    __syncthreads();
#pragma unroll
    for (int off = 1; off < 256; off <<= 1) {
        int t = (tid >= off) ? s[tid - off] : 0;
        __syncthreads();
        s[tid] += t;
        __syncthreads();
    }
    if (i < NN) {
        int excl = boff[blockIdx.x] + s[tid] - v;
        start[i] = excl;
        cursor[i] = excl;
    }
}

__global__ void scatter_kernel(const int* __restrict__ ei,
                               const float* __restrict__ ea,
                               int* __restrict__ cursor,
                               int2* __restrict__ sp) {
    int e = blockIdx.x * blockDim.x + threadIdx.x;
    if (e >= NE) return;
    int d = ei[NE + e];
    int pos = atomicAdd(&cursor[d], 1);
    sp[pos] = make_int2(ei[e], __float_as_int(ea[e]));
}

// ---------------- node pre-projection (layer 1) ----------------
__global__ void pre1_kernel(const float* __restrict__ x,
                            const float* __restrict__ Wp,   // [65][16]
                            const float* __restrict__ bp,   // [16]
                            float* __restrict__ P1) {
    __shared__ float sW[64 * 16];
    __shared__ float sb[16];
    for (int i = threadIdx.x; i < 64 * 16; i += blockDim.x) sW[i] = Wp[i];
    if (threadIdx.x < 16) sb[threadIdx.x] = bp[threadIdx.x];
    __syncthreads();
    int n = blockIdx.x * blockDim.x + threadIdx.x;
    if (n >= NN) return;
    float acc[16];
#pragma unroll
    for (int k = 0; k < 16; ++k) acc[k] = sb[k];
    const float4* xr = (const float4*)(x + (size_t)n * 64);
#pragma unroll
    for (int j4 = 0; j4 < 16; ++j4) {
        float4 xv = xr[j4];
        const float* w = &sW[j4 * 4 * 16];
#pragma unroll
        for (int k = 0; k < 16; ++k) acc[k] += xv.x * w[k];
#pragma unroll
        for (int k = 0; k < 16; ++k) acc[k] += xv.y * w[16 + k];
#pragma unroll
        for (int k = 0; k < 16; ++k) acc[k] += xv.z * w[32 + k];
#pragma unroll
        for (int k = 0; k < 16; ++k) acc[k] += xv.w * w[48 + k];
    }
    float4* o = (float4*)(P1 + (size_t)n * 16);
    o[0] = make_float4(acc[0], acc[1], acc[2], acc[3]);
    o[1] = make_float4(acc[4], acc[5], acc[6], acc[7]);
    o[2] = make_float4(acc[8], acc[9], acc[10], acc[11]);
    o[3] = make_float4(acc[12], acc[13], acc[14], acc[15]);
}

// ---------------- fused gather-max + node MLP ----------------
template <int MODE>
__global__ void gather_kernel(const int2* __restrict__ sp,     // [NE] (src, ea) sorted by dst
                              const int* __restrict__ start,   // [NN+1]
                              const float* __restrict__ Pin,   // [NN][16]
                              const float* __restrict__ wl,    // [16] last row of W_pre
                              const float* __restrict__ Wn,    // [16][16]
                              const float* __restrict__ bn,    // [16]
                              const float* __restrict__ Wo,    // [16][16]
                              const float* __restrict__ bo,    // [16]
                              const float* __restrict__ Wpn,   // [17][16] rows 0..15 (MODE 0)
                              const float* __restrict__ bpn,   // [16] (MODE 0)
                              float* __restrict__ out) {
    __shared__ float swl[16], sbn[16], sbo[16], sbpn[16];
    __shared__ float sWn[256], sWo[256], sWpn[256];
    __shared__ float sAgg[64][17];
    int tid = threadIdx.x;
    if (tid < 256) {
        sWn[tid] = Wn[tid];
        sWo[tid] = Wo[tid];
        if (MODE == 0) sWpn[tid] = Wpn[tid];
    }
    if (tid < 16) {
        swl[tid] = wl[tid];
        sbn[tid] = bn[tid];
        sbo[tid] = bo[tid];
        if (MODE == 0) sbpn[tid] = bpn[tid];
    }
    __syncthreads();

    int l = tid >> 2;        // local node 0..63
    int g = tid & 3;         // dim group 0..3
    int n = blockIdx.x * 64 + l;
    bool valid = (n < NN);

    float acc[4] = {-INFINITY, -INFINITY, -INFINITY, -INFINITY};
    int s0 = 0, s1 = 0;
    if (valid) { s0 = start[n]; s1 = start[n + 1]; }

    int s = s0;
    int2 sv = (s < s1) ? sp[s] : make_int2(0, 0);
    while (s < s1) {
        int2 cur = sv;
        ++s;
        if (s < s1) sv = sp[s];                 // prefetch next pair
        float a = __int_as_float(cur.y);
        const float4* pr = (const float4*)(Pin + (size_t)cur.x * 16);
        float4 v0 = pr[0], v1 = pr[1], v2 = pr[2], v3 = pr[3];
        float t[16] = {v0.x, v0.y, v0.z, v0.w, v1.x, v1.y, v1.z, v1.w,
                       v2.x, v2.y, v2.z, v2.w, v3.x, v3.y, v3.z, v3.w};
#pragma unroll
        for (int j = 0; j < 16; ++j) t[j] = fmaxf(fmaf(a, swl[j], t[j]), 0.0f);
#pragma unroll
        for (int q = 0; q < 4; ++q) {
            int c = g * 4 + q;
            float m = sbn[c];
#pragma unroll
            for (int j = 0; j < 16; ++j) m = fmaf(t[j], sWn[j * 16 + c], m);
            acc[q] = fmaxf(acc[q], m);
        }
    }
    bool empty = (s1 == s0);
#pragma unroll
    for (int q = 0; q < 4; ++q) sAgg[l][g * 4 + q] = empty ? 0.0f : acc[q];
    __syncthreads();

    if (MODE == 0) {
        float h[4];
#pragma unroll
        for (int q = 0; q < 4; ++q) {
            int c = g * 4 + q;
            float o = sbo[c];
#pragma unroll
            for (int j = 0; j < 16; ++j) o = fmaf(sAgg[l][j], sWo[j * 16 + c], o);
            h[q] = elu1(elu1(o));
        }
        __syncthreads();
#pragma unroll
        for (int q = 0; q < 4; ++q) sAgg[l][g * 4 + q] = h[q];
        __syncthreads();
        float p[4];
#pragma unroll
        for (int q = 0; q < 4; ++q) {
            int c = g * 4 + q;
            float o = sbpn[c];
#pragma unroll
            for (int k = 0; k < 16; ++k) o = fmaf(sAgg[l][k], sWpn[k * 16 + c], o);
            p[q] = o;
        }
        if (valid) {
            float4* op = (float4*)(out + (size_t)n * 16 + g * 4);
            *op = make_float4(p[0], p[1], p[2], p[3]);
        }
    } else {
        float oo[4];
#pragma unroll
        for (int q = 0; q < 4; ++q) {
            int c = g * 4 + q;
            float o = sbo[c];
#pragma unroll
            for (int j = 0; j < 16; ++j) o = fmaf(sAgg[l][j], sWo[j * 16 + c], o);
            oo[q] = o;
        }
        __syncthreads();
#pragma unroll
        for (int q = 0; q < 4; ++q) sAgg[l][g * 4 + q] = oo[q];
        __syncthreads();
        float mx = -INFINITY;
#pragma unroll
        for (int j = 0; j < 16; ++j) mx = fmaxf(mx, sAgg[l][j]);
        float sum = 0.0f;
#pragma unroll
        for (int j = 0; j < 16; ++j) sum += expf(sAgg[l][j] - mx);
        float ls = logf(sum) + mx;
        if (valid) {
            float4* op = (float4*)(out + (size_t)n * 16 + g * 4);
            *op = make_float4(oo[0] - ls, oo[1] - ls, oo[2] - ls, oo[3] - ls);
        }
    }
}

extern "C" void kernel_launch(void* const* d_in, const int* in_sizes, int n_in,
                              void* d_out, int out_size, void* d_ws, size_t ws_size,
                              hipStream_t stream) {
    const float* x         = (const float*)d_in[0];
    const float* edge_attr = (const float*)d_in[1];
    const int*   edge_index= (const int*)  d_in[2];
    const float* W_pre1 = (const float*)d_in[3];
    const float* b_pre1 = (const float*)d_in[4];
    const float* W_net1 = (const float*)d_in[5];
    const float* b_net1 = (const float*)d_in[6];
    const float* W_out1 = (const float*)d_in[7];
    const float* b_out1 = (const float*)d_in[8];
    const float* W_pre2 = (const float*)d_in[9];
    const float* b_pre2 = (const float*)d_in[10];
    const float* W_net2 = (const float*)d_in[11];
    const float* b_net2 = (const float*)d_in[12];
    const float* W_out2 = (const float*)d_in[13];
    const float* b_out2 = (const float*)d_in[14];

    char* ws = (char*)d_ws;
    float* P1    = (float*)(ws);                         // 3,200,000 B
    float* P2    = (float*)(ws + 3200000);               // 3,200,000 B
    int2*  sp    = (int2*) (ws + 6400000);               // 6,400,000 B
    int*   start = (int*)  (ws + 12800000);              // 200,004 B
    int*   cursor= (int*)  (ws + 13000256);              // 200,000 B
    int*   deg   = (int*)  (ws + 13200512);              // 200,000 B
    int*   bsum  = (int*)  (ws + 13400512);              // 784 B
    int*   boff  = (int*)  (ws + 13401296);              // 784 B

    const int EDGE_BLOCKS = (NE + 255) / 256;   // 3125
    const int NODE_BLOCKS = (NN + 255) / 256;   // 196
    const int GATH_BLOCKS = (NN + 63) / 64;     // 782

    // ----- CSR setup (shared by both layers) -----
    hipMemsetAsync(deg, 0, (size_t)NN * 4, stream);
    hist_kernel<<<EDGE_BLOCKS, 256, 0, stream>>>(edge_index, deg);
    scan_reduce_kernel<<<SCAN_BLK, 256, 0, stream>>>(deg, bsum);
    scan_partials_kernel<<<1, 256, 0, stream>>>(bsum, boff, start);
    scan_apply_kernel<<<SCAN_BLK, 256, 0, stream>>>(deg, boff, start, cursor);
    scatter_kernel<<<EDGE_BLOCKS, 256, 0, stream>>>(edge_index, edge_attr, cursor, sp);

    // ----- layer 1 -----
    pre1_kernel<<<NODE_BLOCKS, 256, 0, stream>>>(x, W_pre1, b_pre1, P1);
    gather_kernel<0><<<GATH_BLOCKS, 256, 0, stream>>>(sp, start, P1,
        W_pre1 + 64 * 16, W_net1, b_net1, W_out1, b_out1, W_pre2, b_pre2, P2);

    // ----- layer 2 -----
    gather_kernel<1><<<GATH_BLOCKS, 256, 0, stream>>>(sp, start, P2,
        W_pre2 + 16 * 16, W_net2, b_net2, W_out2, b_out2, nullptr, nullptr,
        (float*)d_out);
}